// Round 1
// baseline (1548.246 us; speedup 1.0000x reference)
//
#include <hip/hip_runtime.h>

#define B   64
#define IC  2048
#define ID  16
#define DD  256
#define GB  8    // batches per u-group
#define NSQ 16   // matrix squarings -> exponent 2^16

// ws layout (float offsets):
//  U : GB*IC*DD = 4,194,304
//  C : B*DD*DD  = 4,194,304
//  E : B*DD*DD  = 4,194,304
//  S : 64
// total ~ 50.4 MB

// ---------------- stage 1: u[b,c,:] = x[b,c,:] @ W_c ----------------
// one block per capsule c, covers GB batches; W slice read once per group.
__global__ void u_kernel(const float* __restrict__ caps,
                         const float* __restrict__ W,
                         float* __restrict__ U, int b0) {
    const int c = blockIdx.x;
    const int t = threadIdx.x;           // 256 threads == output dim
    __shared__ float xs[GB][ID];
    if (t < GB * ID)
        xs[t / ID][t % ID] = caps[(((size_t)(b0 + t / ID)) * IC + c) * ID + (t % ID)];
    __syncthreads();
    float acc[GB];
#pragma unroll
    for (int bb = 0; bb < GB; ++bb) acc[bb] = 0.f;
#pragma unroll
    for (int i = 0; i < ID; ++i) {
        float w = W[((size_t)c * ID + i) * DD + t];   // coalesced over t
#pragma unroll
        for (int bb = 0; bb < GB; ++bb) acc[bb] = fmaf(xs[bb][i], w, acc[bb]);
    }
#pragma unroll
    for (int bb = 0; bb < GB; ++bb)
        U[((size_t)bb * IC + c) * DD + t] = acc[bb];
}

// ---------------- stage 2: C_b = U_b^T U_b  (64x64 tile / block) ------------
__global__ void c_kernel(const float* __restrict__ U,
                         float* __restrict__ C, int b0) {
    const int bb   = blockIdx.y;         // batch in group
    const int tile = blockIdx.x;         // 0..15
    const int d0 = (tile >> 2) * 64, e0 = (tile & 3) * 64;
    const int t = threadIdx.x;
    const int r = t >> 4, q = t & 15;    // staging map: row r, 4-col group q
    const int td = t >> 4, te = t & 15;  // compute map: d-quad td, e-quad te
    __shared__ float Ad[16][64];
    __shared__ float Ae[16][64];
    float acc[4][4] = {};
    const float* Ub = U + (size_t)bb * IC * DD;
    for (int kc = 0; kc < IC; kc += 16) {
        const float4 va = *(const float4*)&Ub[((size_t)(kc + r)) * DD + d0 + 4 * q];
        const float4 vb = *(const float4*)&Ub[((size_t)(kc + r)) * DD + e0 + 4 * q];
        __syncthreads();
        *(float4*)&Ad[r][4 * q] = va;
        *(float4*)&Ae[r][4 * q] = vb;
        __syncthreads();
#pragma unroll
        for (int k = 0; k < 16; ++k) {
            float4 a4 = *(const float4*)&Ad[k][4 * td];
            float4 b4 = *(const float4*)&Ae[k][4 * te];
            float ar[4] = {a4.x, a4.y, a4.z, a4.w};
            float br[4] = {b4.x, b4.y, b4.z, b4.w};
#pragma unroll
            for (int i = 0; i < 4; ++i)
#pragma unroll
                for (int j = 0; j < 4; ++j)
                    acc[i][j] = fmaf(ar[i], br[j], acc[i][j]);
        }
    }
    float* Cb = C + (size_t)(b0 + bb) * DD * DD;
#pragma unroll
    for (int i = 0; i < 4; ++i) {
        float4 o = make_float4(acc[i][0], acc[i][1], acc[i][2], acc[i][3]);
        *(float4*)&Cb[((size_t)(d0 + 4 * td + i)) * DD + e0 + 4 * te] = o;  // coalesced
    }
}

// ---------------- trace per batch (normalization scale) ----------------
__global__ void trace_kernel(const float* __restrict__ Dm, float* __restrict__ scale) {
    const int b = blockIdx.x, t = threadIdx.x;
    __shared__ float red[256];
    red[t] = Dm[((size_t)b * DD + t) * DD + t];
    __syncthreads();
    for (int s = 128; s > 0; s >>= 1) {
        if (t < s) red[t] += red[t + s];
        __syncthreads();
    }
    if (t == 0) scale[b] = red[0];
}

// ---------------- E = (D/s) * (D/s), exploiting D == D^T ----------------
__global__ void sq_kernel(const float* __restrict__ Dm, float* __restrict__ E,
                          const float* __restrict__ scale) {
    const int b    = blockIdx.y;
    const int tile = blockIdx.x;
    const int d0 = (tile >> 2) * 64, e0 = (tile & 3) * 64;
    const int t = threadIdx.x;
    const int r = t >> 4, q = t & 15;
    const int td = t >> 4, te = t & 15;
    __shared__ float Ad[16][64];
    __shared__ float Ae[16][64];
    float acc[4][4] = {};
    const float* Db = Dm + (size_t)b * DD * DD;
    const float s = scale[b];
    const float inv = 1.f / (s * s);
    for (int kc = 0; kc < DD; kc += 16) {
        // D[d,k] = D[k,d]: stage row-major rows k -> both operands coalesced
        const float4 va = *(const float4*)&Db[((size_t)(kc + r)) * DD + d0 + 4 * q];
        const float4 vb = *(const float4*)&Db[((size_t)(kc + r)) * DD + e0 + 4 * q];
        __syncthreads();
        *(float4*)&Ad[r][4 * q] = va;
        *(float4*)&Ae[r][4 * q] = vb;
        __syncthreads();
#pragma unroll
        for (int k = 0; k < 16; ++k) {
            float4 a4 = *(const float4*)&Ad[k][4 * td];
            float4 b4 = *(const float4*)&Ae[k][4 * te];
            float ar[4] = {a4.x, a4.y, a4.z, a4.w};
            float br[4] = {b4.x, b4.y, b4.z, b4.w};
#pragma unroll
            for (int i = 0; i < 4; ++i)
#pragma unroll
                for (int j = 0; j < 4; ++j)
                    acc[i][j] = fmaf(ar[i], br[j], acc[i][j]);
        }
    }
    float* Eb = E + (size_t)b * DD * DD;
#pragma unroll
    for (int i = 0; i < 4; ++i) {
        float4 o = make_float4(acc[i][0] * inv, acc[i][1] * inv,
                               acc[i][2] * inv, acc[i][3] * inv);
        *(float4*)&Eb[((size_t)(d0 + 4 * td + i)) * DD + e0 + 4 * te] = o;
    }
}

// ---------------- extract dominant eigenvector ----------------
// D^N ~ lambda^N v v^T : pick column jmax (max diagonal == max |v_i|),
// normalize; entry jmax is v_jmax^2/|...| > 0 -> matches reference sign fix.
__global__ void extract_kernel(const float* __restrict__ Dm, float* __restrict__ out) {
    const int b = blockIdx.x, t = threadIdx.x;
    __shared__ float sval[256];
    __shared__ int   sidx[256];
    const float* Db = Dm + (size_t)b * DD * DD;
    sval[t] = Db[(size_t)t * DD + t];
    sidx[t] = t;
    __syncthreads();
    for (int s = 128; s > 0; s >>= 1) {
        if (t < s) {
            if (sval[t + s] > sval[t]) { sval[t] = sval[t + s]; sidx[t] = sidx[t + s]; }
        }
        __syncthreads();
    }
    const int jmax = sidx[0];
    __syncthreads();
    const float x = Db[(size_t)t * DD + jmax];
    sval[t] = x * x;
    __syncthreads();
    for (int s = 128; s > 0; s >>= 1) {
        if (t < s) sval[t] += sval[t + s];
        __syncthreads();
    }
    out[(size_t)b * DD + t] = x / sqrtf(sval[0]);
}

extern "C" void kernel_launch(void* const* d_in, const int* in_sizes, int n_in,
                              void* d_out, int out_size, void* d_ws, size_t ws_size,
                              hipStream_t stream) {
    const float* caps = (const float*)d_in[0];   // (64, 2048, 16)
    const float* W    = (const float*)d_in[1];   // (2048, 16, 256)
    float* out = (float*)d_out;                  // (64, 256)
    float* ws  = (float*)d_ws;

    float* U  = ws;
    float* Cb = ws + 4194304;
    float* Eb = ws + 8388608;
    float* Sc = ws + 12582912;

    // stages 1+2 in 8 batch-groups (u buffer consumed hot from L2/L3)
    for (int g = 0; g < 8; ++g) {
        u_kernel<<<IC, 256, 0, stream>>>(caps, W, U, g * GB);
        c_kernel<<<dim3(16, GB), 256, 0, stream>>>(U, Cb, g * GB);
    }

    // eigen: 16 trace-normalized matrix squarings (exponent 2^16)
    float* ping = Cb;
    float* pong = Eb;
    for (int it = 0; it < NSQ; ++it) {
        trace_kernel<<<B, 256, 0, stream>>>(ping, Sc);
        sq_kernel<<<dim3(16, B), 256, 0, stream>>>(ping, pong, Sc);
        float* tmp = ping; ping = pong; pong = tmp;
    }

    extract_kernel<<<B, 256, 0, stream>>>(ping, out);
}

// Round 2
// 1268.532 us; speedup vs baseline: 1.2205x; 1.2205x over previous
//
#include <hip/hip_runtime.h>

#define B   64
#define IC  2048
#define ID  16
#define DD  256
#define GB  8     // batches per u-group
#define NSQ 12    // matrix squarings -> exponent 2^12
#define NPI 15    // power-iteration finish: total exponent 4096*16 = 65536
#define KS  8     // K-chunks in c_kernel (occupancy)

// ws layout (float offsets):
//  U  : GB*IC*DD        = 4,194,304   @ 0
//  C  : B*DD*DD         = 4,194,304   @ 4,194,304
//  Sc : (NSQ+1)*64 pad  = 2,048       @ 8,388,608
//  E  : B*DD*DD         = 4,194,304   @ 8,390,656
//  total ~50.3 MB

// ---------------- stage 1: u[b,c,:] = x[b,c,:] @ W_c ----------------
__global__ void u_kernel(const float* __restrict__ caps,
                         const float* __restrict__ W,
                         float* __restrict__ U, int b0) {
    const int c = blockIdx.x;
    const int t = threadIdx.x;           // 256 threads == output dim
    __shared__ float xs[GB][ID];
    if (t < GB * ID)
        xs[t / ID][t % ID] = caps[(((size_t)(b0 + t / ID)) * IC + c) * ID + (t % ID)];
    __syncthreads();
    float acc[GB];
#pragma unroll
    for (int bb = 0; bb < GB; ++bb) acc[bb] = 0.f;
#pragma unroll
    for (int i = 0; i < ID; ++i) {
        float w = W[((size_t)c * ID + i) * DD + t];   // coalesced over t
#pragma unroll
        for (int bb = 0; bb < GB; ++bb) acc[bb] = fmaf(xs[bb][i], w, acc[bb]);
    }
#pragma unroll
    for (int bb = 0; bb < GB; ++bb)
        U[((size_t)bb * IC + c) * DD + t] = acc[bb];
}

// ---------------- stage 2: C_b += Uchunk^T Uchunk (64x64 tile, K=256) -------
// grid (16 tiles, GB batches, KS chunks); atomicAdd into zeroed C.
// Diagonal-tile threads also accumulate partial trace into Sc0[b].
__global__ void c_kernel(const float* __restrict__ U,
                         float* __restrict__ C,
                         float* __restrict__ Sc0, int b0) {
    const int bb   = blockIdx.y;
    const int tile = blockIdx.x;
    const int kch  = blockIdx.z;
    const int d0 = (tile >> 2) * 64, e0 = (tile & 3) * 64;
    const int t = threadIdx.x;
    const int r = t >> 4, q = t & 15;
    const int td = t >> 4, te = t & 15;
    __shared__ float Ad[16][64];
    __shared__ float Ae[16][64];
    float acc[4][4] = {};
    const float* Ub = U + (size_t)bb * IC * DD;
    const int k0 = kch * (IC / KS);
    for (int kc = k0; kc < k0 + IC / KS; kc += 16) {
        const float4 va = *(const float4*)&Ub[((size_t)(kc + r)) * DD + d0 + 4 * q];
        const float4 vb = *(const float4*)&Ub[((size_t)(kc + r)) * DD + e0 + 4 * q];
        __syncthreads();
        *(float4*)&Ad[r][4 * q] = va;
        *(float4*)&Ae[r][4 * q] = vb;
        __syncthreads();
#pragma unroll
        for (int k = 0; k < 16; ++k) {
            float4 a4 = *(const float4*)&Ad[k][4 * td];
            float4 b4 = *(const float4*)&Ae[k][4 * te];
            float ar[4] = {a4.x, a4.y, a4.z, a4.w};
            float br[4] = {b4.x, b4.y, b4.z, b4.w};
#pragma unroll
            for (int i = 0; i < 4; ++i)
#pragma unroll
                for (int j = 0; j < 4; ++j)
                    acc[i][j] = fmaf(ar[i], br[j], acc[i][j]);
        }
    }
    float* Cb = C + (size_t)(b0 + bb) * DD * DD;
#pragma unroll
    for (int i = 0; i < 4; ++i)
#pragma unroll
        for (int j = 0; j < 4; ++j)
            atomicAdd(&Cb[((size_t)(d0 + 4 * td + i)) * DD + e0 + 4 * te + j], acc[i][j]);
    if (d0 == e0 && td == te)
        atomicAdd(&Sc0[b0 + bb], acc[0][0] + acc[1][1] + acc[2][2] + acc[3][3]);
}

// ---------------- E = (D/s)^2 with fused trace(E) -> s_out ----------------
__global__ void sq_kernel(const float* __restrict__ Dm, float* __restrict__ E,
                          const float* __restrict__ s_in, float* __restrict__ s_out) {
    const int b    = blockIdx.y;
    const int tile = blockIdx.x;
    const int d0 = (tile >> 2) * 64, e0 = (tile & 3) * 64;
    const int t = threadIdx.x;
    const int r = t >> 4, q = t & 15;
    const int td = t >> 4, te = t & 15;
    __shared__ float Ad[16][64];
    __shared__ float Ae[16][64];
    float acc[4][4] = {};
    const float* Db = Dm + (size_t)b * DD * DD;
    const float s = s_in[b];
    const float inv = 1.f / (s * s);
    for (int kc = 0; kc < DD; kc += 16) {
        const float4 va = *(const float4*)&Db[((size_t)(kc + r)) * DD + d0 + 4 * q];
        const float4 vb = *(const float4*)&Db[((size_t)(kc + r)) * DD + e0 + 4 * q];
        __syncthreads();
        *(float4*)&Ad[r][4 * q] = va;
        *(float4*)&Ae[r][4 * q] = vb;
        __syncthreads();
#pragma unroll
        for (int k = 0; k < 16; ++k) {
            float4 a4 = *(const float4*)&Ad[k][4 * td];
            float4 b4 = *(const float4*)&Ae[k][4 * te];
            float ar[4] = {a4.x, a4.y, a4.z, a4.w};
            float br[4] = {b4.x, b4.y, b4.z, b4.w};
#pragma unroll
            for (int i = 0; i < 4; ++i)
#pragma unroll
                for (int j = 0; j < 4; ++j)
                    acc[i][j] = fmaf(ar[i], br[j], acc[i][j]);
        }
    }
#pragma unroll
    for (int i = 0; i < 4; ++i)
#pragma unroll
        for (int j = 0; j < 4; ++j)
            acc[i][j] *= inv;
    float* Eb = E + (size_t)b * DD * DD;
#pragma unroll
    for (int i = 0; i < 4; ++i) {
        float4 o = make_float4(acc[i][0], acc[i][1], acc[i][2], acc[i][3]);
        *(float4*)&Eb[((size_t)(d0 + 4 * td + i)) * DD + e0 + 4 * te] = o;
    }
    if (d0 == e0 && td == te)
        atomicAdd(&s_out[b], acc[0][0] + acc[1][1] + acc[2][2] + acc[3][3]);
}

// ---------------- finish: column start + NPI power iterations ----------------
__global__ void finish_kernel(const float* __restrict__ Dm, float* __restrict__ out) {
    const int b = blockIdx.x, t = threadIdx.x;
    const float* Db = Dm + (size_t)b * DD * DD;
    __shared__ float vs[DD];
    __shared__ float red[DD];
    __shared__ int   ridx[DD];
    // start: column jmax (max diagonal); read as row (D symmetric) -> coalesced
    red[t] = Db[(size_t)t * DD + t];
    ridx[t] = t;
    __syncthreads();
    for (int s = 128; s > 0; s >>= 1) {
        if (t < s && red[t + s] > red[t]) { red[t] = red[t + s]; ridx[t] = ridx[t + s]; }
        __syncthreads();
    }
    const int jmax0 = ridx[0];
    __syncthreads();
    float v = Db[(size_t)jmax0 * DD + t];
    // power iterations: v <- D v, renormalize by max|v|
    for (int it = 0; it < NPI; ++it) {
        vs[t] = v;
        __syncthreads();
        float a = 0.f;
        const float* row = Db + (size_t)t * DD;
#pragma unroll 4
        for (int j = 0; j < DD; j += 4) {
            float4 d4 = *(const float4*)&row[j];
            a = fmaf(d4.x, vs[j], a);
            a = fmaf(d4.y, vs[j + 1], a);
            a = fmaf(d4.z, vs[j + 2], a);
            a = fmaf(d4.w, vs[j + 3], a);
        }
        red[t] = fabsf(a);
        __syncthreads();
        for (int s = 128; s > 0; s >>= 1) {
            if (t < s && red[t + s] > red[t]) red[t] = red[t + s];
            __syncthreads();
        }
        const float m = red[0];
        __syncthreads();
        v = a / m;
    }
    // final: normalize, sign-fix at argmax|v| (first occurrence on tie)
    vs[t] = v;
    red[t] = v * v;
    __syncthreads();
    for (int s = 128; s > 0; s >>= 1) {
        if (t < s) red[t] += red[t + s];
        __syncthreads();
    }
    const float nrm = sqrtf(red[0]);
    __syncthreads();
    red[t] = fabsf(v);
    ridx[t] = t;
    __syncthreads();
    for (int s = 128; s > 0; s >>= 1) {
        if (t < s && red[t + s] > red[t]) { red[t] = red[t + s]; ridx[t] = ridx[t + s]; }
        __syncthreads();
    }
    const float sgn = (vs[ridx[0]] < 0.f) ? -1.f : 1.f;
    out[(size_t)b * DD + t] = sgn * v / nrm;
}

extern "C" void kernel_launch(void* const* d_in, const int* in_sizes, int n_in,
                              void* d_out, int out_size, void* d_ws, size_t ws_size,
                              hipStream_t stream) {
    const float* caps = (const float*)d_in[0];   // (64, 2048, 16)
    const float* W    = (const float*)d_in[1];   // (2048, 16, 256)
    float* out = (float*)d_out;                  // (64, 256)
    float* ws  = (float*)d_ws;

    float* U  = ws;
    float* Cb = ws + 4194304;
    float* Sc = ws + 8388608;    // (NSQ+1) slots of 64 floats, padded to 2048
    float* Eb = ws + 8390656;

    // zero C (atomic accumulation target) + all trace slots in one memset
    hipMemsetAsync(Cb, 0, (size_t)(4194304 + 2048) * sizeof(float), stream);

    // stages 1+2 in 8 batch-groups; c_kernel K-split 8-way for occupancy
    for (int g = 0; g < 8; ++g) {
        u_kernel<<<IC, 256, 0, stream>>>(caps, W, U, g * GB);
        c_kernel<<<dim3(16, GB, KS), 256, 0, stream>>>(U, Cb, Sc, g * GB);
    }

    // eigen: 12 trace-normalized squarings (trace fused into producer)
    float* ping = Cb;
    float* pong = Eb;
    for (int it = 0; it < NSQ; ++it) {
        sq_kernel<<<dim3(16, B), 256, 0, stream>>>(ping, pong, Sc + it * 64, Sc + (it + 1) * 64);
        float* tmp = ping; ping = pong; pong = tmp;
    }

    // NSQ even -> final matrix is back in Cb
    finish_kernel<<<B, 256, 0, stream>>>(ping, out);
}